// Round 5
// baseline (675.595 us; speedup 1.0000x reference)
//
#include <hip/hip_runtime.h>
#include <stdint.h>

typedef unsigned short u16;
typedef unsigned u32;
typedef float f32x4 __attribute__((ext_vector_type(4)));
typedef f32x4 __attribute__((may_alias)) f32x4a;
typedef __bf16 bf16x8 __attribute__((ext_vector_type(8)));
typedef u32 u32x4 __attribute__((ext_vector_type(4)));
typedef float f32x16 __attribute__((ext_vector_type(16)));

#define S_LEN 1024
#define D_DIM 64
#define BHN   64

__device__ __forceinline__ float bf2f(u16 b) {
  return __builtin_bit_cast(float, (u32)b << 16);
}
// load 8 consecutive fp32, round to bf16x8 (compiler emits v_cvt_pk_bf16_f32)
__device__ __forceinline__ bf16x8 cvt8(const float* p) {
  f32x4 a = *reinterpret_cast<const f32x4a*>(p);
  f32x4 b = *reinterpret_cast<const f32x4a*>(p + 4);
  bf16x8 r;
#pragma unroll
  for (int j = 0; j < 4; ++j) { r[j] = (__bf16)a[j]; r[4 + j] = (__bf16)b[j]; }
  return r;
}

// ---------------- fused attention (fp32 in / fp32 out, bf16 MFMA inside) -------------
// block: 256 thr = 4 waves, one (bh, 32-row q tile). wave w owns k-cols [256w,256w+256).
// Phase 1 uses SWAPPED MFMA (kf as A, qa as B): lane (l31,half) holds
// P[q0+l31][t*32 + koff(r,half)], koff(r,h) = (r&3) + 8*(r>>2) + 4h.
// KEY: no cross-lane exchange at all (R4's permlane32_swap had unverifiable
// direction semantics and failed correctness). MFMA only requires A-slot and
// B-slot k-indices to MATCH (any bijection): keep P in its natural slot order
// kappa(h,j) = (j&3) + 8*(j>>2) + 4h and gather V rows in the SAME permuted
// order. Attn stores are re-indexed identically (two 16B runs per frag).
// LDS:
//   [0, 4096)       mask bias table [4][8][2][16] f32, pre-permuted to acc layout
//   [4096, 12800)   O-reduce accumulator [32][68] f32 (ds_add_f32 atomics)
//   [12800, 13312)  rowsum [4][32] f32
//   [13312, 13440)  inv [32] f32
#define MB_OFF     0
#define ORED_OFF   4096
#define RS_OFF     (ORED_OFF + 32 * 68 * 4)
#define INV_OFF    (RS_OFF + 512)
#define SMEM_BYTES (INV_OFF + 128)

// (256,3): pfrag(64) + oacc(32 AGPR) + PV pipeline temps ~ 140-160 regs.
// (256,4) spills (R1: +88 MB scratch writes, 187->262 us). Keep 3.
__global__ __launch_bounds__(256, 3) void attn_kernel(
    const float* __restrict__ Q, const float* __restrict__ K, const int* __restrict__ Mk,
    const float* __restrict__ V, float* __restrict__ outO, float* __restrict__ outA) {
  __shared__ __align__(16) char smem[SMEM_BYTES];
  const int tid = threadIdx.x;
  const int wave = tid >> 6, lane = tid & 63;
  const int l31 = lane & 31, half = lane >> 5;

  // XCD swizzle: ids congruent mod 8 share an XCD; 32 q-tiles of one bh are
  // time-contiguous there so K/V (512 KB) stay L2-resident (FETCH 122->45 MB).
  const int id = blockIdx.x;                  // 0..2047
  const int xcd = id & 7, ord = id >> 3;
  const int bh = xcd * 8 + (ord >> 5);
  const int q0 = (ord & 31) << 5;             // q-tile * 32

  float* mbias = (float*)(smem + MB_OFF);     // [wave][t][hi][r] -> 0 or -1e9
  float* ored = (float*)(smem + ORED_OFF);    // [32][68] atomic O accumulator
  float* rs_lds = (float*)(smem + RS_OFF);    // [4][32]
  float* inv_lds = (float*)(smem + INV_OFF);  // [32]

  // mask -> bias table, PRE-PERMUTED into the 32x32 MFMA acc layout so phase 1
  // reads it as dependency-free broadcast LDS loads. bias=-1e9 makes
  // exp2((acc+bias)*c) == 0 exactly (bit-identical to the old *mf path).
  const int* maskp = Mk + ((size_t)bh << 10);
  for (int i = tid; i < 1024; i += 256) {
    const int w = i >> 8, rem = i & 255;
    const int t = rem >> 5, hi = (rem >> 4) & 1, r = rem & 15;
    const int col = (w << 8) + (t << 5) + (r & 3) + ((r >> 2) << 3) + (hi << 2);
    mbias[i] = (maskp[col] == 0) ? -1.0e9f : 0.0f;
  }
  for (int i = tid; i < 32 * 68; i += 256) ored[i] = 0.0f;

  // ---- Q fragments: lane holds Q[q0+l31][ks*16 + half*8 + j] (used as B now) ----
  const float* qb = Q + (((size_t)bh << 10) + q0 + l31) * D_DIM + half * 8;
  bf16x8 qa[4];
#pragma unroll
  for (int ks = 0; ks < 4; ++ks) qa[ks] = cvt8(qb + ks * 16);

  __syncthreads();  // mbias + ored ready

  const int colbase = wave * 256;
  const float* kb0 = K + ((size_t)bh << 10) * D_DIM + half * 8;
  const float* mbw = mbias + (wave << 8) + (half << 4);

  bf16x8 pfrag[16];  // wave's exp(P) chunk [32 x 256], slot j holds k-offset kappa(h,j)
  float rs = 0.0f;   // lane-local rowsum (bf16-rounded values)

  // ---- phase 1: QK^T (swapped) -> exp -> pack in natural slot order ----
#pragma unroll
  for (int t = 0; t < 8; ++t) {
    const float* kb = kb0 + (size_t)(colbase + t * 32 + l31) * D_DIM;
    f32x16 acc = 0.0f;
#pragma unroll
    for (int ks = 0; ks < 4; ++ks) {
      bf16x8 kf = cvt8(kb + ks * 16);
      // swapped: K rows as A, Q rows as B -> acc[r] = P[q0+l31][t*32 + koff(r,half)]
      acc = __builtin_amdgcn_mfma_f32_32x32x16_bf16(kf, qa[ks], acc, 0, 0, 0);
    }
    const float* mb = mbw + (t << 5);
    u32 w[8];
#pragma unroll
    for (int i = 0; i < 8; ++i) {
      // score = acc/8; exp(score) = exp2((acc + bias) * 0.125*log2(e))
      const float p0 = exp2f((acc[2 * i] + mb[2 * i]) * 0.18033688f);
      const float p1 = exp2f((acc[2 * i + 1] + mb[2 * i + 1]) * 0.18033688f);
      const u16 b0 = __builtin_bit_cast(u16, (__bf16)p0);
      const u16 b1 = __builtin_bit_cast(u16, (__bf16)p1);
      rs += bf2f(b0) + bf2f(b1);  // bf16-consistent numerator/denominator
      w[i] = ((u32)b1 << 16) | (u32)b0;
    }
    // slot j of pfrag[2t]   = acc[j]   -> k-offset kappa(half,j)      (k 0..15)
    // slot j of pfrag[2t+1] = acc[8+j] -> k-offset 16 + kappa(half,j) (k 16..31)
    u32x4 f0 = {w[0], w[1], w[2], w[3]};
    u32x4 f1 = {w[4], w[5], w[6], w[7]};
    pfrag[2 * t] = __builtin_bit_cast(bf16x8, f0);
    pfrag[2 * t + 1] = __builtin_bit_cast(bf16x8, f1);
  }

  // ---- row sums: lane-local + one cross-half swap, then cross-wave via LDS ----
  const float rsw = rs + __shfl_xor(rs, 32, 64);
  if (half == 0) rs_lds[(wave << 5) + l31] = rsw;
  __syncthreads();
  if (tid < 32) {
    float s = rs_lds[tid] + rs_lds[32 + tid] + rs_lds[64 + tid] + rs_lds[96 + tid];
    inv_lds[tid] = 1.0f / s;
  }
  __syncthreads();

  // ---- PV: V gathered in the SAME permuted k-order kappa(half,jj), so the
  // B slots match pfrag's A slots. Hand-pipelined one kk ahead. ----
  f32x16 oacc0 = 0.0f, oacc1 = 0.0f;
  const float* vb = V + (((size_t)bh << 10) + colbase + half * 4) * D_DIM + l31;
  float cv0[8], cv1[8];
#pragma unroll
  for (int jj = 0; jj < 8; ++jj) {
    const int vo = ((jj & 3) + 8 * (jj >> 2)) * D_DIM;
    cv0[jj] = vb[vo]; cv1[jj] = vb[vo + 32];
  }
#pragma unroll
  for (int kk = 0; kk < 16; ++kk) {
    float nv0[8], nv1[8];
    if (kk < 15) {
      const float* vn = vb + (size_t)(kk + 1) * 16 * D_DIM;
#pragma unroll
      for (int jj = 0; jj < 8; ++jj) {
        const int vo = ((jj & 3) + 8 * (jj >> 2)) * D_DIM;
        nv0[jj] = vn[vo]; nv1[jj] = vn[vo + 32];
      }
    }
    bf16x8 b0, b1;
#pragma unroll
    for (int jj = 0; jj < 8; ++jj) { b0[jj] = (__bf16)cv0[jj]; b1[jj] = (__bf16)cv1[jj]; }
    oacc0 = __builtin_amdgcn_mfma_f32_32x32x16_bf16(pfrag[kk], b0, oacc0, 0, 0, 0);
    oacc1 = __builtin_amdgcn_mfma_f32_32x32x16_bf16(pfrag[kk], b1, oacc1, 0, 0, 0);
    if (kk < 15) {
#pragma unroll
      for (int jj = 0; jj < 8; ++jj) { cv0[jj] = nv0[jj]; cv1[jj] = nv1[jj]; }
    }
  }

  // ---- attn write (fp32): slot j of frag (t,f) is column
  // colbase + t*32 + f*16 + kappa(half,j) -> two 16B runs per frag.
  // Plain cached stores (R2: nontemporal caused 1.8x write amplification). ----
  const float myinv = inv_lds[l31];
  float* ab = outA + ((size_t)bh << 20) + ((size_t)(q0 + l31) << 10) + colbase + half * 4;
#pragma unroll
  for (int t = 0; t < 8; ++t) {
#pragma unroll
    for (int f = 0; f < 2; ++f) {
      bf16x8 pf = pfrag[2 * t + f];
      f32x4 lo, hi;
#pragma unroll
      for (int j = 0; j < 4; ++j) {
        lo[j] = (float)pf[j] * myinv;       // cols +0..3   (kappa j=0..3)
        hi[j] = (float)pf[4 + j] * myinv;   // cols +8..11  (kappa j=4..7)
      }
      *reinterpret_cast<f32x4a*>(ab + t * 32 + f * 16) = lo;
      *reinterpret_cast<f32x4a*>(ab + t * 32 + f * 16 + 8) = hi;
    }
  }

  // ---- cross-wave O reduction via LDS float atomics ----
#pragma unroll
  for (int r = 0; r < 16; ++r) {
    const int row = (r & 3) + ((r >> 2) << 3) + (half << 2);
    atomicAdd(&ored[row * 68 + l31], oacc0[r]);
    atomicAdd(&ored[row * 68 + 32 + l31], oacc1[r]);
  }
  // lgkm-only barrier: attn stores keep draining during the tiny O epilogue.
  asm volatile("s_waitcnt lgkmcnt(0)" ::: "memory");
  __builtin_amdgcn_s_barrier();
  __builtin_amdgcn_sched_barrier(0);

  const int orow = tid >> 3;
  const int oc = (tid & 7) * 8;
  const float iv = inv_lds[orow];
  f32x4 o0 = *reinterpret_cast<const f32x4a*>(ored + orow * 68 + oc);
  f32x4 o1 = *reinterpret_cast<const f32x4a*>(ored + orow * 68 + oc + 4);
#pragma unroll
  for (int jj = 0; jj < 4; ++jj) { o0[jj] *= iv; o1[jj] *= iv; }
  float* ob = outO + (((size_t)bh << 10) + q0 + orow) * D_DIM + oc;
  *reinterpret_cast<f32x4a*>(ob) = o0;
  *reinterpret_cast<f32x4a*>(ob + 4) = o1;
}

extern "C" void kernel_launch(void* const* d_in, const int* in_sizes, int n_in,
                              void* d_out, int out_size, void* d_ws, size_t ws_size,
                              hipStream_t stream) {
  (void)in_sizes; (void)n_in; (void)out_size; (void)d_ws; (void)ws_size;
  const float* Q = (const float*)d_in[0];
  const float* K = (const float*)d_in[1];
  const float* V = (const float*)d_in[2];
  const int*   M = (const int*)d_in[3];
  float* outO = (float*)d_out;
  float* outA = outO + (size_t)BHN * S_LEN * D_DIM;  // attn follows output, flat

  attn_kernel<<<dim3(BHN * (S_LEN / 32)), dim3(256), 0, stream>>>(Q, K, M, V, outO, outA);
}